// Round 5
// baseline (100.593 us; speedup 1.0000x reference)
//
#include <hip/hip_runtime.h>

#define FSRS_S_MIN 0.01f
#define FSRS_S_MAX 36500.0f
#define T_LEN 64
#define CHUNK 8
#define NCHUNK (T_LEN / CHUNK)

// 2 batch elements per thread: float4 loads (16B/lane), 2 independent
// recurrence chains per lane, grid = exactly 1 block/CU (256 blocks).
__global__ __launch_bounds__(256, 1) void fsrs2_kernel(
    const float* __restrict__ inputs,    // [64, B, 2] (elapsed, rating)
    const float* __restrict__ delta_ts,  // [B]
    const float* __restrict__ w,         // [14]
    const int*   __restrict__ seq_lens,  // [B]
    float* __restrict__ out,             // [3, B]
    int B)
{
    const int g  = blockIdx.x * blockDim.x + threadIdx.x;  // pair index
    const int B2 = B >> 1;
    if (g >= B2) return;

    // small per-thread loads issued first
    const int2   L2  = ((const int2*)seq_lens)[g];
    const float2 dt2 = ((const float2*)delta_ts)[g];
    const int LmA = L2.x - 1, LmB = L2.y - 1;    // in [0,63]

    // ---- uniform scalar constants ----
    const float w0 = w[0],  w1 = w[1],  w2 = w[2],  w3 = w[3];
    const float w4 = w[4],  w5 = w[5],  w6 = w[6],  w7 = w[7];
    const float w8 = w[8],  w9 = w[9],  w10 = w[10], w11 = w[11];
    const float w12 = w[12], w13 = w[13];

    const float LOG2E = 1.4426950408889634f;
    const float L09   = -0.15200309344504997f;   // log2(0.9)

    const float a0 = w0 * w1;                    // s0 = a0*rating + b0
    const float b0 = w0 * (1.0f - w1);
    const float a1 = w2 * w3;                    // d0 = clamp(a1*rating + b1)
    const float b1 = w2 * (1.0f - 4.0f * w3);
    const float c_nd = 1.0f - w5;                // nd mix
    const float b_nd = w5 * (w2 * (1.0f - w3));
    const float lw6 = w6  * LOG2E;               // exp(w6)       = exp2(lw6)
    const float g9  = w9  * LOG2E;               // exp((1-r)w9)  = exp2((1-r)g9)
    const float g13 = w13 * LOG2E;               // exp((1-r)w13) = exp2((1-r)g13)

    // one FSRS2 step for one element (t, Lm1 fold to constants after unroll)
    auto step = [&](int t, int Lm1, float elapsed, float rating,
                    float& s, float& d, float& res_s, float& res_d) {
        const float ss     = fmaxf(s, FSRS_S_MIN);
        const float inv_ss = __builtin_amdgcn_rcpf(ss);
        const float lss    = log2f(ss);
        const float r      = exp2f(elapsed * inv_ss * L09);  // 0.9^(elapsed/ss)
        const float omr    = 1.0f - r;

        float nd = fmaf(w4, rating - 3.0f, d);
        nd = fmaf(c_nd, nd, b_nd);
        nd = fminf(fmaxf(nd, 1.0f), 10.0f);
        const float lnd = log2f(nd);

        const bool up = rating > 1.0f;
        const float eP = up ? fmaf(w7, lnd, fmaf(w8, lss, lw6))
                            : fmaf(w11, lnd, w12 * lss);
        const float eG = omr * (up ? g9 : g13);
        const float pw = exp2f(eP);
        const float gg = exp2f(eG) - 1.0f;

        float ns = up ? ss * fmaf(pw, gg, 1.0f) : (w10 * pw) * gg;

        if (t == 0) {                             // folds at compile time
            ns = fmaf(a0, rating, b0);
            nd = fminf(fmaxf(fmaf(a1, rating, b1), 1.0f), 10.0f);
        }
        s = fminf(fmaxf(ns, FSRS_S_MIN), FSRS_S_MAX);
        d = nd;
        if (t == Lm1) { res_s = s; res_d = d; }   // 2 cndmask
    };

    // inputs row t = B float2 = B2 float4; pair (2g,2g+1) is one float4
    const float4* __restrict__ inp = (const float4*)inputs;

    // ---- 3-buffer register rotation, prefetch depth 2 (static indices) ----
    float4 buf[3][CHUNK];
    #pragma unroll
    for (int i = 0; i < CHUNK; ++i) buf[0][i] = inp[(size_t)(0 * CHUNK + i) * B2 + g];
    #pragma unroll
    for (int i = 0; i < CHUNK; ++i) buf[1][i] = inp[(size_t)(1 * CHUNK + i) * B2 + g];

    float sA = 0.0f, dA = 0.0f, rsA = 0.0f, rdA = 0.0f;
    float sB = 0.0f, dB = 0.0f, rsB = 0.0f, rdB = 0.0f;

    #pragma unroll
    for (int c = 0; c < NCHUNK; ++c) {
        if (c + 2 < NCHUNK) {
            #pragma unroll
            for (int i = 0; i < CHUNK; ++i)
                buf[(c + 2) % 3][i] = inp[(size_t)((c + 2) * CHUNK + i) * B2 + g];
        }
        #pragma unroll
        for (int i = 0; i < CHUNK; ++i) {
            const int t = c * CHUNK + i;          // compile-time constant
            const float4 v = buf[c % 3][i];
            step(t, LmA, v.x, v.y, sA, dA, rsA, rdA);
            step(t, LmB, v.z, v.w, sB, dB, rsB, rdB);
        }
    }

    const float retA = exp2f(dt2.x * __builtin_amdgcn_rcpf(rsA) * L09);
    const float retB = exp2f(dt2.y * __builtin_amdgcn_rcpf(rsB) * L09);

    float2* __restrict__ out2 = (float2*)out;     // [3, B2] float2 rows
    out2[g]          = make_float2(retA, retB);
    out2[B2 + g]     = make_float2(rsA,  rsB);
    out2[2 * B2 + g] = make_float2(rdA,  rdB);
}

extern "C" void kernel_launch(void* const* d_in, const int* in_sizes, int n_in,
                              void* d_out, int out_size, void* d_ws, size_t ws_size,
                              hipStream_t stream) {
    const float* inputs   = (const float*)d_in[0];   // [64, B, 2] f32
    const float* delta_ts = (const float*)d_in[1];   // [B] f32
    const float* w        = (const float*)d_in[2];   // [14] f32
    const int*   seq_lens = (const int*)d_in[3];     // [B] i32
    float* out = (float*)d_out;                      // [3, B] f32

    const int B = in_sizes[1];                       // 131072 (even)
    const int pairs = B >> 1;
    const int block = 256;
    const int grid  = (pairs + block - 1) / block;   // 256 blocks = 1/CU
    fsrs2_kernel<<<grid, block, 0, stream>>>(inputs, delta_ts, w, seq_lens, out, B);
}